// Round 3
// baseline (776.967 us; speedup 1.0000x reference)
//
#include <hip/hip_runtime.h>
#include <math.h>

#define T_STEPS 2048
#define B_SZ 16
#define D_SZ 1024
#define N_SZ 64
#define M_ROWS (T_STEPS * B_SZ)   // 32768
#define NOUT (4 * N_SZ)           // 256

// ---------------------------------------------------------------------------
// DPP-based full-wave (64-lane) sum, result uniform across all lanes.
// ---------------------------------------------------------------------------
#define DPP_ADD(x, ctrl)                                                      \
  ((x) + __int_as_float(__builtin_amdgcn_update_dpp(                          \
             0, __float_as_int(x), (ctrl), 0xF, 0xF, true)))

__device__ __forceinline__ float wave_sum64(float v) {
  v = DPP_ADD(v, 0xB1);   // quad_perm [1,0,3,2]  : xor 1
  v = DPP_ADD(v, 0x4E);   // quad_perm [2,3,0,1]  : xor 2
  v = DPP_ADD(v, 0x141);  // row_half_mirror      : xor 4
  v = DPP_ADD(v, 0x140);  // row_mirror           : xor 8
  const int vi = __float_as_int(v);
  const float a = __int_as_float(__builtin_amdgcn_readlane(vi, 0));
  const float b = __int_as_float(__builtin_amdgcn_readlane(vi, 16));
  const float c = __int_as_float(__builtin_amdgcn_readlane(vi, 32));
  const float d = __int_as_float(__builtin_amdgcn_readlane(vi, 48));
  return (a + b) + (c + d);
}

// ---------------------------------------------------------------------------
// Kernel 1: proj[m, n] = dot(x[m, :], W[n, :])   (M=32768, K=1024, N=256)
// 128x128 block tile, 256 threads, 8x8 per thread. LDS [k][row] w/ pad 132.
// av reads conflict-free (mi consecutive within wave); bv 4-way (accepted).
// ---------------------------------------------------------------------------
__global__ __launch_bounds__(256) void gemm_proj(const float* __restrict__ x,
                                                 const float* __restrict__ W,
                                                 float* __restrict__ proj) {
  __shared__ float xs[32][132];
  __shared__ float ws[32][132];
  const int tid = threadIdx.x;
  const int n0 = blockIdx.x * 128;   // 2 n-blocks
  const int m0 = blockIdx.y * 128;   // 256 m-blocks
  const int mi = tid >> 4;           // 0..15 -> rows mi*8..+7
  const int ni = tid & 15;           // 0..15 -> cols ni*8..+7

  float acc[8][8];
#pragma unroll
  for (int r = 0; r < 8; ++r)
#pragma unroll
    for (int c = 0; c < 8; ++c) acc[r][c] = 0.f;

  for (int k0 = 0; k0 < D_SZ; k0 += 32) {
#pragma unroll
    for (int rep = 0; rep < 4; ++rep) {
      const int f = tid + rep * 256;      // 0..1023
      const int row = f >> 3;             // 0..127
      const int c4 = (f & 7) * 4;
      const float4 xv = *reinterpret_cast<const float4*>(
          &x[(size_t)(m0 + row) * D_SZ + k0 + c4]);
      xs[c4 + 0][row] = xv.x; xs[c4 + 1][row] = xv.y;
      xs[c4 + 2][row] = xv.z; xs[c4 + 3][row] = xv.w;
      const float4 wv = *reinterpret_cast<const float4*>(
          &W[(size_t)(n0 + row) * D_SZ + k0 + c4]);
      ws[c4 + 0][row] = wv.x; ws[c4 + 1][row] = wv.y;
      ws[c4 + 2][row] = wv.z; ws[c4 + 3][row] = wv.w;
    }
    __syncthreads();
#pragma unroll
    for (int k = 0; k < 32; ++k) {
      float av[8], bv[8];
      *reinterpret_cast<float4*>(&av[0]) =
          *reinterpret_cast<const float4*>(&xs[k][mi * 8]);
      *reinterpret_cast<float4*>(&av[4]) =
          *reinterpret_cast<const float4*>(&xs[k][mi * 8 + 4]);
      *reinterpret_cast<float4*>(&bv[0]) =
          *reinterpret_cast<const float4*>(&ws[k][ni * 8]);
      *reinterpret_cast<float4*>(&bv[4]) =
          *reinterpret_cast<const float4*>(&ws[k][ni * 8 + 4]);
#pragma unroll
      for (int r = 0; r < 8; ++r)
#pragma unroll
        for (int c = 0; c < 8; ++c)
          acc[r][c] = fmaf(av[r], bv[c], acc[r][c]);
    }
    __syncthreads();
  }

#pragma unroll
  for (int r = 0; r < 8; ++r) {
    const size_t row = (size_t)(m0 + mi * 8 + r);
    float4 o0, o1;
    o0.x = acc[r][0]; o0.y = acc[r][1]; o0.z = acc[r][2]; o0.w = acc[r][3];
    o1.x = acc[r][4]; o1.y = acc[r][5]; o1.z = acc[r][6]; o1.w = acc[r][7];
    *reinterpret_cast<float4*>(&proj[row * NOUT + n0 + ni * 8]) = o0;
    *reinterpret_cast<float4*>(&proj[row * NOUT + n0 + ni * 8 + 4]) = o1;
  }
}

// ---------------------------------------------------------------------------
// Kernel 2: per (t,b) row of proj, IN-PLACE repack:
//   new row = [ (kn[j], q[j]) x64 | (v[j], decay[j]) x64 ]
// ---------------------------------------------------------------------------
__global__ __launch_bounds__(256) void norm_gate(float* __restrict__ proj,
                                                 const float* __restrict__ b_gate) {
  const int wid = threadIdx.x >> 6;
  const int lane = threadIdx.x & 63;
  const int m = blockIdx.x * 4 + wid;
  float* p = proj + (size_t)m * NOUT;
  const float kf = p[lane];
  const float vf = p[64 + lane];
  const float qf = p[128 + lane];
  const float gf = p[192 + lane];
  const float bg = b_gate[lane];
  const float ss = wave_sum64(kf * kf);
  const float kn = kf / (sqrtf(ss) + 1e-6f);
  const float dec = 1.f / (1.f + expf(-(gf + bg)));
  asm volatile("s_waitcnt vmcnt(0)" ::: "memory");
  float2* pp = reinterpret_cast<float2*>(p);
  float2 a; a.x = kn; a.y = qf;
  float2 c; c.x = vf; c.y = dec;
  pp[lane] = a;        // (kn, q)
  pp[64 + lane] = c;   // (v, dec)
}

// ---------------------------------------------------------------------------
// Kernel 3: sequential scan, TWO rows (b,i0) and (b,i0+32) per wave.
// Shared kn/q loads and shared r3 = kn.q reduction; interleaved dual chains.
// 512 waves in 256 blocks of 2 waves. Ping-pong prefetch 4..8 steps ahead.
// ---------------------------------------------------------------------------
__global__ __launch_bounds__(128) void scan_kernel(const float* __restrict__ proj,
                                                   const float* __restrict__ S0,
                                                   float* __restrict__ out,
                                                   float* __restrict__ Sfin) {
  const int wid = threadIdx.x >> 6;     // 0..1
  const int lane = threadIdx.x & 63;
  const int gw = blockIdx.x * 2 + wid;  // 0..511
  const int b = gw >> 5;                // 0..15
  const int i0 = gw & 31;
  const int i1 = i0 + 32;

  float Sa = S0[(size_t)b * 4096 + i0 * 64 + lane];
  float Sb = S0[(size_t)b * 4096 + i1 * 64 + lane];
  const float2* base = reinterpret_cast<const float2*>(proj);  // row = 128 f2

  float2 knqA[4], vdaA[4], vdbA[4];
  float2 knqB[4], vdaB[4], vdbB[4];

#define LOADG(knq, vda, vdb, t)                                               \
  {                                                                           \
    _Pragma("unroll")                                                         \
    for (int u = 0; u < 4; ++u) {                                             \
      const float2* p = base + (size_t)(((t) + u) * B_SZ + b) * 128;          \
      knq[u] = p[lane];                                                       \
      vda[u] = p[64 + i0];                                                    \
      vdb[u] = p[64 + i1];                                                    \
    }                                                                         \
  }

#define PROC(knq, vda, vdb, t)                                                \
  {                                                                           \
    _Pragma("unroll")                                                         \
    for (int u = 0; u < 4; ++u) {                                             \
      const float kn = knq[u].x;                                              \
      const float qv = knq[u].y;                                              \
      const float r3 = wave_sum64(kn * qv);                                   \
      const float r1a = wave_sum64(Sa * kn);                                  \
      const float r1b = wave_sum64(Sb * kn);                                  \
      const float r2a = wave_sum64(Sa * qv);                                  \
      const float r2b = wave_sum64(Sb * qv);                                  \
      const float da = vda[u].x - r1a;                                        \
      const float db = vdb[u].x - r1b;                                        \
      Sa = fmaf(vda[u].y, Sa, da * kn);                                       \
      Sb = fmaf(vdb[u].y, Sb, db * kn);                                       \
      const float sqa = fmaf(vda[u].y, r2a, da * r3);                         \
      const float sqb = fmaf(vdb[u].y, r2b, db * r3);                         \
      if ((lane & 31) == 0) {                                                 \
        const float sq = (lane == 0) ? sqa : sqb;                             \
        const int ii = (lane == 0) ? i0 : i1;                                 \
        out[(size_t)((t) + u) * (B_SZ * N_SZ) + b * N_SZ + ii] =              \
            sq * sq * __fdividef(1.f, 1.f + __expf(-sq));                     \
      }                                                                       \
    }                                                                         \
  }

  LOADG(knqA, vdaA, vdbA, 0)
  for (int t0 = 0; t0 < T_STEPS; t0 += 8) {
    LOADG(knqB, vdaB, vdbB, t0 + 4)
    PROC(knqA, vdaA, vdbA, t0)
    const int tn = (t0 + 8 <= T_STEPS - 4) ? (t0 + 8) : (T_STEPS - 4);
    LOADG(knqA, vdaA, vdbA, tn)
    PROC(knqB, vdaB, vdbB, t0 + 4)
  }
  Sfin[(size_t)b * 4096 + i0 * 64 + lane] = Sa;
  Sfin[(size_t)b * 4096 + i1 * 64 + lane] = Sb;
#undef LOADG
#undef PROC
}

// ---------------------------------------------------------------------------
extern "C" void kernel_launch(void* const* d_in, const int* in_sizes, int n_in,
                              void* d_out, int out_size, void* d_ws, size_t ws_size,
                              hipStream_t stream) {
  const float* x      = (const float*)d_in[0];
  const float* S0     = (const float*)d_in[1];
  const float* W      = (const float*)d_in[2];
  const float* b_gate = (const float*)d_in[3];
  float* out  = (float*)d_out;
  float* proj = (float*)d_ws;                   // 32768 * 256 * 4B = 33.5 MB

  hipLaunchKernelGGL(gemm_proj, dim3(2, M_ROWS / 128), dim3(256), 0, stream,
                     x, W, proj);
  hipLaunchKernelGGL(norm_gate, dim3(M_ROWS / 4), dim3(256), 0, stream,
                     proj, b_gate);
  hipLaunchKernelGGL(scan_kernel, dim3(256), dim3(128), 0, stream,
                     proj, S0, out, out + (size_t)T_STEPS * B_SZ * N_SZ);
}

// Round 5
// 673.999 us; speedup vs baseline: 1.1528x; 1.1528x over previous
//
#include <hip/hip_runtime.h>
#include <math.h>

#define T_STEPS 2048
#define B_SZ 16
#define D_SZ 1024
#define N_SZ 64
#define M_ROWS (T_STEPS * B_SZ)   // 32768
#define NOUT (4 * N_SZ)           // 256
#define U_BLK 8
#define NBLK (T_STEPS / U_BLK)    // 256

// ---------------------------------------------------------------------------
// DPP reduction: 4 butterfly stages -> row-uniform, 2 row_bcast adds -> total
// in lanes 48..63, readlane 63 -> wave-uniform scalar (SGPR).
// dpp ctrl/masks must be compile-time constants -> template params.
// ---------------------------------------------------------------------------
template <int CTRL, int RMASK, bool BC>
__device__ __forceinline__ float dpp_add(float v) {
  return v + __int_as_float(__builtin_amdgcn_update_dpp(
                 0, __float_as_int(v), CTRL, RMASK, 0xF, BC));
}
__device__ __forceinline__ float wave_red(float v) {
  v = dpp_add<0xB1, 0xF, true>(v);    // quad_perm xor 1
  v = dpp_add<0x4E, 0xF, true>(v);    // quad_perm xor 2
  v = dpp_add<0x141, 0xF, true>(v);   // row_half_mirror (xor 4)
  v = dpp_add<0x140, 0xF, true>(v);   // row_mirror (xor 8)
  v = dpp_add<0x142, 0xA, false>(v);  // row_bcast15 -> rows 1,3
  v = dpp_add<0x143, 0xC, false>(v);  // row_bcast31 -> rows 2,3
  return __int_as_float(__builtin_amdgcn_readlane(__float_as_int(v), 63));
}

// ---------------------------------------------------------------------------
// Kernel 1: proj[m, n] = dot(x[m, :], W[n, :])  (unchanged from R2)
// ---------------------------------------------------------------------------
__global__ __launch_bounds__(256) void gemm_proj(const float* __restrict__ x,
                                                 const float* __restrict__ W,
                                                 float* __restrict__ proj) {
  __shared__ float xs[32][132];
  __shared__ float ws[32][132];
  const int tid = threadIdx.x;
  const int n0 = blockIdx.x * 128;
  const int m0 = blockIdx.y * 128;
  const int mi = tid >> 4;
  const int ni = tid & 15;

  float acc[8][8];
#pragma unroll
  for (int r = 0; r < 8; ++r)
#pragma unroll
    for (int c = 0; c < 8; ++c) acc[r][c] = 0.f;

  for (int k0 = 0; k0 < D_SZ; k0 += 32) {
#pragma unroll
    for (int rep = 0; rep < 4; ++rep) {
      const int f = tid + rep * 256;
      const int row = f >> 3;
      const int c4 = (f & 7) * 4;
      const float4 xv = *reinterpret_cast<const float4*>(
          &x[(size_t)(m0 + row) * D_SZ + k0 + c4]);
      xs[c4 + 0][row] = xv.x; xs[c4 + 1][row] = xv.y;
      xs[c4 + 2][row] = xv.z; xs[c4 + 3][row] = xv.w;
      const float4 wv = *reinterpret_cast<const float4*>(
          &W[(size_t)(n0 + row) * D_SZ + k0 + c4]);
      ws[c4 + 0][row] = wv.x; ws[c4 + 1][row] = wv.y;
      ws[c4 + 2][row] = wv.z; ws[c4 + 3][row] = wv.w;
    }
    __syncthreads();
#pragma unroll
    for (int k = 0; k < 32; ++k) {
      float av[8], bv[8];
      *reinterpret_cast<float4*>(&av[0]) =
          *reinterpret_cast<const float4*>(&xs[k][mi * 8]);
      *reinterpret_cast<float4*>(&av[4]) =
          *reinterpret_cast<const float4*>(&xs[k][mi * 8 + 4]);
      *reinterpret_cast<float4*>(&bv[0]) =
          *reinterpret_cast<const float4*>(&ws[k][ni * 8]);
      *reinterpret_cast<float4*>(&bv[4]) =
          *reinterpret_cast<const float4*>(&ws[k][ni * 8 + 4]);
#pragma unroll
      for (int r = 0; r < 8; ++r)
#pragma unroll
        for (int c = 0; c < 8; ++c)
          acc[r][c] = fmaf(av[r], bv[c], acc[r][c]);
    }
    __syncthreads();
  }

#pragma unroll
  for (int r = 0; r < 8; ++r) {
    const size_t row = (size_t)(m0 + mi * 8 + r);
    float4 o0, o1;
    o0.x = acc[r][0]; o0.y = acc[r][1]; o0.z = acc[r][2]; o0.w = acc[r][3];
    o1.x = acc[r][4]; o1.y = acc[r][5]; o1.z = acc[r][6]; o1.w = acc[r][7];
    *reinterpret_cast<float4*>(&proj[row * NOUT + n0 + ni * 8]) = o0;
    *reinterpret_cast<float4*>(&proj[row * NOUT + n0 + ni * 8 + 4]) = o1;
  }
}

// ---------------------------------------------------------------------------
// Kernel 2: per (t,b) row of proj, IN-PLACE repack:
//   row = [ (kn[j], q[j]) x64 | (v[j], decay[j]) x64 ]
// ---------------------------------------------------------------------------
__global__ __launch_bounds__(256) void norm_gate(float* __restrict__ proj,
                                                 const float* __restrict__ b_gate) {
  const int wid = threadIdx.x >> 6;
  const int lane = threadIdx.x & 63;
  const int m = blockIdx.x * 4 + wid;
  float* p = proj + (size_t)m * NOUT;
  const float kf = p[lane];
  const float vf = p[64 + lane];
  const float qf = p[128 + lane];
  const float gf = p[192 + lane];
  const float bg = b_gate[lane];
  const float ss = wave_red(kf * kf);
  const float kn = kf / (sqrtf(ss) + 1e-6f);
  const float dec = 1.f / (1.f + expf(-(gf + bg)));
  asm volatile("s_waitcnt vmcnt(0)" ::: "memory");
  float2* pp = reinterpret_cast<float2*>(p);
  float2 a; a.x = kn; a.y = qf;
  float2 c; c.x = vf; c.y = dec;
  pp[lane] = a;
  pp[64 + lane] = c;
}

// ---------------------------------------------------------------------------
// Kernel 3: Gram precompute. M is 8x8 per (b, blk):
//   M[a][c] = kn_a . kn_c            for c > a   (G)
//   M[a][c] = q_a  . kn_c (=H[c][a]) for c <= a  (H, diag = kn_a.q_a at [a][a])
// One wave per (b, blk, a).  gram[(b*NBLK+blk)*64 + a*8 + c]
// ---------------------------------------------------------------------------
__global__ __launch_bounds__(256) void gram_kernel(const float* __restrict__ proj,
                                                   float* __restrict__ gram) {
  const int wid = threadIdx.x >> 6;
  const int lane = threadIdx.x & 63;
  const int gw = blockIdx.x * 4 + wid;      // 0..32767
  const int a = gw & 7;
  const int grp = gw >> 3;                  // 0..4095  = b*NBLK + blk
  const int blk = grp & (NBLK - 1);
  const int b = grp >> 8;
  const int t0 = blk * U_BLK;
  const float2* base = reinterpret_cast<const float2*>(proj);

  float2 knq[8];
#pragma unroll
  for (int c = 0; c < 8; ++c)
    knq[c] = base[(size_t)((t0 + c) * B_SZ + b) * 128 + lane];
  const float2 mine = base[(size_t)((t0 + a) * B_SZ + b) * 128 + lane];

  float row[8];
#pragma unroll
  for (int c = 0; c < 8; ++c) {
    const float lhs = (c > a) ? mine.x : mine.y;   // kn_a or q_a
    row[c] = wave_red(lhs * knq[c].x);
  }
  if (lane == 0) {
    float* dst = gram + ((size_t)grp * 64 + a * 8);
    float4 r0, r1;
    r0.x = row[0]; r0.y = row[1]; r0.z = row[2]; r0.w = row[3];
    r1.x = row[4]; r1.y = row[5]; r1.z = row[6]; r1.w = row[7];
    *reinterpret_cast<float4*>(dst) = r0;
    *reinterpret_cast<float4*>(dst + 4) = r1;
  }
}

// ---------------------------------------------------------------------------
// Kernel 4: scan, block-parallel reformulation. One wave per (b,i), U=8.
// Per block: 16 independent base reductions + scalar recurrence (coefs <= 1)
// + one fused S update.  All u/w loops fully unrolled (static reg indexing).
// ---------------------------------------------------------------------------
__global__ __launch_bounds__(256, 1) void scan_kernel(
    const float* __restrict__ proj, const float* __restrict__ gram,
    const float* __restrict__ S0, float* __restrict__ out,
    float* __restrict__ Sfin) {
  const int wid = threadIdx.x >> 6;
  const int lane = threadIdx.x & 63;
  const int gw = blockIdx.x * 4 + wid;      // 0..1023
  const int b = gw >> 6;
  const int i = gw & 63;

  float S = S0[(size_t)b * 4096 + i * 64 + lane];
  const float2* base = reinterpret_cast<const float2*>(proj);
  const size_t outbase = (size_t)b * N_SZ + i;

  float2 knqA[8], vdA[8], knqB[8], vdB[8];

#define LOADB(knq, vd, blkv)                                                  \
  {                                                                           \
    const int t0_ = (blkv) * U_BLK;                                           \
    _Pragma("unroll")                                                         \
    for (int u = 0; u < 8; ++u) {                                             \
      const float2* p = base + (size_t)((t0_ + u) * B_SZ + b) * 128;          \
      knq[u] = p[lane];                                                       \
      vd[u] = p[64 + i];                                                      \
    }                                                                         \
  }

#define PROC(knq, vd, blkv)                                                   \
  {                                                                           \
    const int t0_ = (blkv) * U_BLK;                                           \
    const float* gm = gram +                                                  \
        __builtin_amdgcn_readfirstlane((b * NBLK + (blkv)) * 64);             \
    float gmv[64];                                                            \
    _Pragma("unroll")                                                         \
    for (int z = 0; z < 64; ++z) gmv[z] = gm[z];                              \
    float ra[8], rb[8];                                                       \
    _Pragma("unroll")                                                         \
    for (int u = 0; u < 8; ++u) ra[u] = wave_red(S * knq[u].x);               \
    _Pragma("unroll")                                                         \
    for (int u = 0; u < 8; ++u) rb[u] = wave_red(S * knq[u].y);               \
    float P = 1.f, ew[8], sqv[8];                                             \
    _Pragma("unroll")                                                         \
    for (int u = 0; u < 8; ++u) {                                             \
      float r = P * ra[u];                                                    \
      float sqs = P * rb[u];                                                  \
      _Pragma("unroll")                                                       \
      for (int w = 0; w < u; ++w) {                                           \
        r = fmaf(ew[w], gmv[w * 8 + u], r);        /* G[w][u] */              \
        sqs = fmaf(ew[w], gmv[u * 8 + w], sqs);    /* H[w][u] */              \
      }                                                                       \
      const float dec = vd[u].y;                                              \
      const float d = vd[u].x - r;                                            \
      sqs = fmaf(dec, sqs, d * gmv[u * 8 + u]);    /* H[u][u] */              \
      sqv[u] = sqs;                                                           \
      _Pragma("unroll")                                                       \
      for (int w = 0; w < u; ++w) ew[w] *= dec;                               \
      ew[u] = d;                                                              \
      P *= dec;                                                               \
    }                                                                         \
    float corr = 0.f;                                                         \
    _Pragma("unroll")                                                         \
    for (int w = 0; w < 8; ++w) corr = fmaf(ew[w], knq[w].x, corr);           \
    S = fmaf(P, S, corr);                                                     \
    if (lane == 0) {                                                          \
      _Pragma("unroll")                                                       \
      for (int u = 0; u < 8; ++u) {                                           \
        const float sq = sqv[u];                                              \
        out[(size_t)(t0_ + u) * (B_SZ * N_SZ) + outbase] =                    \
            sq * sq * __fdividef(1.f, 1.f + __expf(-sq));                     \
      }                                                                       \
    }                                                                         \
  }

  LOADB(knqA, vdA, 0)
  for (int blk = 0; blk < NBLK; blk += 2) {
    LOADB(knqB, vdB, blk + 1)
    PROC(knqA, vdA, blk)
    const int nb = (blk + 2 < NBLK) ? (blk + 2) : (NBLK - 1);
    LOADB(knqA, vdA, nb)
    PROC(knqB, vdB, blk + 1)
  }
  Sfin[(size_t)b * 4096 + i * 64 + lane] = S;
#undef LOADB
#undef PROC
}

// ---------------------------------------------------------------------------
extern "C" void kernel_launch(void* const* d_in, const int* in_sizes, int n_in,
                              void* d_out, int out_size, void* d_ws, size_t ws_size,
                              hipStream_t stream) {
  const float* x      = (const float*)d_in[0];
  const float* S0     = (const float*)d_in[1];
  const float* W      = (const float*)d_in[2];
  const float* b_gate = (const float*)d_in[3];
  float* out  = (float*)d_out;
  float* proj = (float*)d_ws;                       // 33.55 MB
  float* gram = (float*)((char*)d_ws + (size_t)M_ROWS * NOUT * 4);  // +1 MB

  hipLaunchKernelGGL(gemm_proj, dim3(2, M_ROWS / 128), dim3(256), 0, stream,
                     x, W, proj);
  hipLaunchKernelGGL(norm_gate, dim3(M_ROWS / 4), dim3(256), 0, stream,
                     proj, b_gate);
  hipLaunchKernelGGL(gram_kernel, dim3(32768 / 4), dim3(256), 0, stream,
                     proj, gram);
  hipLaunchKernelGGL(scan_kernel, dim3(256), dim3(256), 0, stream,
                     proj, gram, S0, out, out + (size_t)T_STEPS * B_SZ * N_SZ);
}

// Round 6
// 654.562 us; speedup vs baseline: 1.1870x; 1.0297x over previous
//
#include <hip/hip_runtime.h>
#include <math.h>

#define T_STEPS 2048
#define B_SZ 16
#define D_SZ 1024
#define N_SZ 64
#define M_ROWS (T_STEPS * B_SZ)   // 32768
#define NOUT (4 * N_SZ)           // 256
#define U_BLK 8
#define NBLK (T_STEPS / U_BLK)    // 256

// ---------------------------------------------------------------------------
// DPP reduction: 4 butterfly stages -> row-uniform, 2 row_bcast adds -> total
// in lanes 48..63, readlane 63 -> wave-uniform scalar (SGPR).
// ---------------------------------------------------------------------------
template <int CTRL, int RMASK, bool BC>
__device__ __forceinline__ float dpp_add(float v) {
  return v + __int_as_float(__builtin_amdgcn_update_dpp(
                 0, __float_as_int(v), CTRL, RMASK, 0xF, BC));
}
__device__ __forceinline__ float wave_red(float v) {
  v = dpp_add<0xB1, 0xF, true>(v);    // quad_perm xor 1
  v = dpp_add<0x4E, 0xF, true>(v);    // quad_perm xor 2
  v = dpp_add<0x141, 0xF, true>(v);   // row_half_mirror (xor 4)
  v = dpp_add<0x140, 0xF, true>(v);   // row_mirror (xor 8)
  v = dpp_add<0x142, 0xA, false>(v);  // row_bcast15 -> rows 1,3
  v = dpp_add<0x143, 0xC, false>(v);  // row_bcast31 -> rows 2,3
  return __int_as_float(__builtin_amdgcn_readlane(__float_as_int(v), 63));
}

// ---------------------------------------------------------------------------
// Kernel 1: proj[m, n] = dot(x[m, :], W[n, :])  (unchanged)
// ---------------------------------------------------------------------------
__global__ __launch_bounds__(256) void gemm_proj(const float* __restrict__ x,
                                                 const float* __restrict__ W,
                                                 float* __restrict__ proj) {
  __shared__ float xs[32][132];
  __shared__ float ws[32][132];
  const int tid = threadIdx.x;
  const int n0 = blockIdx.x * 128;
  const int m0 = blockIdx.y * 128;
  const int mi = tid >> 4;
  const int ni = tid & 15;

  float acc[8][8];
#pragma unroll
  for (int r = 0; r < 8; ++r)
#pragma unroll
    for (int c = 0; c < 8; ++c) acc[r][c] = 0.f;

  for (int k0 = 0; k0 < D_SZ; k0 += 32) {
#pragma unroll
    for (int rep = 0; rep < 4; ++rep) {
      const int f = tid + rep * 256;
      const int row = f >> 3;
      const int c4 = (f & 7) * 4;
      const float4 xv = *reinterpret_cast<const float4*>(
          &x[(size_t)(m0 + row) * D_SZ + k0 + c4]);
      xs[c4 + 0][row] = xv.x; xs[c4 + 1][row] = xv.y;
      xs[c4 + 2][row] = xv.z; xs[c4 + 3][row] = xv.w;
      const float4 wv = *reinterpret_cast<const float4*>(
          &W[(size_t)(n0 + row) * D_SZ + k0 + c4]);
      ws[c4 + 0][row] = wv.x; ws[c4 + 1][row] = wv.y;
      ws[c4 + 2][row] = wv.z; ws[c4 + 3][row] = wv.w;
    }
    __syncthreads();
#pragma unroll
    for (int k = 0; k < 32; ++k) {
      float av[8], bv[8];
      *reinterpret_cast<float4*>(&av[0]) =
          *reinterpret_cast<const float4*>(&xs[k][mi * 8]);
      *reinterpret_cast<float4*>(&av[4]) =
          *reinterpret_cast<const float4*>(&xs[k][mi * 8 + 4]);
      *reinterpret_cast<float4*>(&bv[0]) =
          *reinterpret_cast<const float4*>(&ws[k][ni * 8]);
      *reinterpret_cast<float4*>(&bv[4]) =
          *reinterpret_cast<const float4*>(&ws[k][ni * 8 + 4]);
#pragma unroll
      for (int r = 0; r < 8; ++r)
#pragma unroll
        for (int c = 0; c < 8; ++c)
          acc[r][c] = fmaf(av[r], bv[c], acc[r][c]);
    }
    __syncthreads();
  }

#pragma unroll
  for (int r = 0; r < 8; ++r) {
    const size_t row = (size_t)(m0 + mi * 8 + r);
    float4 o0, o1;
    o0.x = acc[r][0]; o0.y = acc[r][1]; o0.z = acc[r][2]; o0.w = acc[r][3];
    o1.x = acc[r][4]; o1.y = acc[r][5]; o1.z = acc[r][6]; o1.w = acc[r][7];
    *reinterpret_cast<float4*>(&proj[row * NOUT + n0 + ni * 8]) = o0;
    *reinterpret_cast<float4*>(&proj[row * NOUT + n0 + ni * 8 + 4]) = o1;
  }
}

// ---------------------------------------------------------------------------
// Kernel 2: per (t,b) row, in-place repack: [ (kn,q) x64 | (v,dec) x64 ]
// ---------------------------------------------------------------------------
__global__ __launch_bounds__(256) void norm_gate(float* __restrict__ proj,
                                                 const float* __restrict__ b_gate) {
  const int wid = threadIdx.x >> 6;
  const int lane = threadIdx.x & 63;
  const int m = blockIdx.x * 4 + wid;
  float* p = proj + (size_t)m * NOUT;
  const float kf = p[lane];
  const float vf = p[64 + lane];
  const float qf = p[128 + lane];
  const float gf = p[192 + lane];
  const float bg = b_gate[lane];
  const float ss = wave_red(kf * kf);
  const float kn = kf / (sqrtf(ss) + 1e-6f);
  const float dec = 1.f / (1.f + expf(-(gf + bg)));
  asm volatile("s_waitcnt vmcnt(0)" ::: "memory");
  float2* pp = reinterpret_cast<float2*>(p);
  float2 a; a.x = kn; a.y = qf;
  float2 c; c.x = vf; c.y = dec;
  pp[lane] = a;
  pp[64 + lane] = c;
}

// ---------------------------------------------------------------------------
// Kernel 3: Gram precompute (unchanged).
//   M[a][c] = kn_a . kn_c  (c > a) ; q_a . kn_c (c <= a, diag kn.q at [a][a])
// ---------------------------------------------------------------------------
__global__ __launch_bounds__(256) void gram_kernel(const float* __restrict__ proj,
                                                   float* __restrict__ gram) {
  const int wid = threadIdx.x >> 6;
  const int lane = threadIdx.x & 63;
  const int gw = blockIdx.x * 4 + wid;
  const int a = gw & 7;
  const int grp = gw >> 3;                  // b*NBLK + blk
  const int blk = grp & (NBLK - 1);
  const int b = grp >> 8;
  const int t0 = blk * U_BLK;
  const float2* base = reinterpret_cast<const float2*>(proj);

  float2 knq[8];
#pragma unroll
  for (int c = 0; c < 8; ++c)
    knq[c] = base[(size_t)((t0 + c) * B_SZ + b) * 128 + lane];
  const float2 mine = base[(size_t)((t0 + a) * B_SZ + b) * 128 + lane];

  float row[8];
#pragma unroll
  for (int c = 0; c < 8; ++c) {
    const float lhs = (c > a) ? mine.x : mine.y;
    row[c] = wave_red(lhs * knq[c].x);
  }
  if (lane == 0) {
    float* dst = gram + ((size_t)grp * 64 + a * 8);
    float4 r0, r1;
    r0.x = row[0]; r0.y = row[1]; r0.z = row[2]; r0.w = row[3];
    r1.x = row[4]; r1.y = row[5]; r1.z = row[6]; r1.w = row[7];
    *reinterpret_cast<float4*>(dst) = r0;
    *reinterpret_cast<float4*>(dst + 4) = r1;
  }
}

// ---------------------------------------------------------------------------
// Kernel 4: scan. 256 blocks x 4 waves; block -> (b, i-group of 4).
// LDS double-buffered staging of 8 proj rows + gram per U-block:
//   iter k: issue global loads for block k+1 -> regs; compute block k from
//   lds[k&1]; ds_write regs -> lds[(k+1)&1]; one barrier.
// Gram coefficients: lane z holds gram[z]; accessed via constant readlane.
// ---------------------------------------------------------------------------
__global__ __launch_bounds__(256, 1) void scan_kernel(
    const float* __restrict__ proj, const float* __restrict__ gram,
    const float* __restrict__ S0, float* __restrict__ out,
    float* __restrict__ Sfin) {
  const int wid = threadIdx.x >> 6;     // 0..3
  const int lane = threadIdx.x & 63;
  const int b = blockIdx.x >> 4;        // 16 blocks per b
  const int i = ((blockIdx.x & 15) << 2) | wid;

  __shared__ float lds[2][U_BLK * 256 + 64];   // 2 x 8448 B = 16.9 KB

  float S = S0[(size_t)b * 4096 + i * 64 + lane];

  const int r0 = wid * 2;           // this wave stages rows r0, r0+1
  float4 st0, st1;
  float stg = 0.f;

#define STAGE_LOAD(blkv)                                                      \
  {                                                                           \
    const size_t g0 = ((size_t)(((blkv) * U_BLK + r0) * B_SZ + b)) * NOUT;    \
    st0 = *reinterpret_cast<const float4*>(&proj[g0 + lane * 4]);             \
    st1 = *reinterpret_cast<const float4*>(&proj[g0 + (size_t)B_SZ * NOUT +   \
                                                 lane * 4]);                  \
    if (wid == 0) stg = gram[((size_t)b * NBLK + (blkv)) * 64 + lane];        \
  }

#define STAGE_WRITE(bufv)                                                     \
  {                                                                           \
    *reinterpret_cast<float4*>(&lds[bufv][r0 * 256 + lane * 4]) = st0;        \
    *reinterpret_cast<float4*>(&lds[bufv][(r0 + 1) * 256 + lane * 4]) = st1;  \
    if (wid == 0) lds[bufv][U_BLK * 256 + lane] = stg;                        \
  }

#define GM(idx) __int_as_float(                                               \
    __builtin_amdgcn_readlane(__float_as_int(gv), (idx)))

  // prologue: stage block 0 into buffer 0
  STAGE_LOAD(0)
  STAGE_WRITE(0)
  __syncthreads();

  for (int blk = 0; blk < NBLK; ++blk) {
    const int buf = blk & 1;
    if (blk + 1 < NBLK) STAGE_LOAD(blk + 1)

    // ---- compute block blk from lds[buf] ----
    float2 knqv[8], vdv[8];
#pragma unroll
    for (int u = 0; u < 8; ++u) {
      knqv[u] = *reinterpret_cast<const float2*>(&lds[buf][u * 256 + lane * 2]);
      vdv[u] = *reinterpret_cast<const float2*>(&lds[buf][u * 256 + 128 + i * 2]);
    }
    const float gv = lds[buf][U_BLK * 256 + lane];

    float ra[8], rb[8];
#pragma unroll
    for (int u = 0; u < 8; ++u) ra[u] = wave_red(S * knqv[u].x);
#pragma unroll
    for (int u = 0; u < 8; ++u) rb[u] = wave_red(S * knqv[u].y);

    float P = 1.f, ew[8], sqv[8];
#pragma unroll
    for (int u = 0; u < 8; ++u) {
      float r = P * ra[u];
      float sqs = P * rb[u];
#pragma unroll
      for (int w = 0; w < u; ++w) {
        r = fmaf(ew[w], GM(w * 8 + u), r);       // G[w][u]
        sqs = fmaf(ew[w], GM(u * 8 + w), sqs);   // H[w][u]
      }
      const float dec = vdv[u].y;
      const float d = vdv[u].x - r;
      sqs = fmaf(dec, sqs, d * GM(u * 8 + u));   // diag
      sqv[u] = sqs;
#pragma unroll
      for (int w = 0; w < u; ++w) ew[w] *= dec;
      ew[u] = d;
      P *= dec;
    }
    float corr = 0.f;
#pragma unroll
    for (int w = 0; w < 8; ++w) corr = fmaf(ew[w], knqv[w].x, corr);
    S = fmaf(P, S, corr);

    if (lane == 0) {
      const size_t ob = (size_t)blk * U_BLK * (B_SZ * N_SZ) + b * N_SZ + i;
#pragma unroll
      for (int u = 0; u < 8; ++u) {
        const float sq = sqv[u];
        out[ob + (size_t)u * (B_SZ * N_SZ)] =
            sq * sq * __fdividef(1.f, 1.f + __expf(-sq));
      }
    }
    // ---- end compute ----

    if (blk + 1 < NBLK) STAGE_WRITE((blk + 1) & 1)
    __syncthreads();
  }

  Sfin[(size_t)b * 4096 + i * 64 + lane] = S;
#undef STAGE_LOAD
#undef STAGE_WRITE
#undef GM
}

// ---------------------------------------------------------------------------
extern "C" void kernel_launch(void* const* d_in, const int* in_sizes, int n_in,
                              void* d_out, int out_size, void* d_ws, size_t ws_size,
                              hipStream_t stream) {
  const float* x      = (const float*)d_in[0];
  const float* S0     = (const float*)d_in[1];
  const float* W      = (const float*)d_in[2];
  const float* b_gate = (const float*)d_in[3];
  float* out  = (float*)d_out;
  float* proj = (float*)d_ws;                       // 33.55 MB
  float* gram = (float*)((char*)d_ws + (size_t)M_ROWS * NOUT * 4);  // +1 MB

  hipLaunchKernelGGL(gemm_proj, dim3(2, M_ROWS / 128), dim3(256), 0, stream,
                     x, W, proj);
  hipLaunchKernelGGL(norm_gate, dim3(M_ROWS / 4), dim3(256), 0, stream,
                     proj, b_gate);
  hipLaunchKernelGGL(gram_kernel, dim3(32768 / 4), dim3(256), 0, stream,
                     proj, gram);
  hipLaunchKernelGGL(scan_kernel, dim3(256), dim3(256), 0, stream,
                     proj, gram, S0, out, out + (size_t)T_STEPS * B_SZ * N_SZ);
}

// Round 7
// 590.705 us; speedup vs baseline: 1.3153x; 1.1081x over previous
//
#include <hip/hip_runtime.h>
#include <math.h>

#define T_STEPS 2048
#define B_SZ 16
#define D_SZ 1024
#define N_SZ 64
#define M_ROWS (T_STEPS * B_SZ)   // 32768
#define NOUT (4 * N_SZ)           // 256
#define U_BLK 8
#define NBLK (T_STEPS / U_BLK)    // 256

// ---------------------------------------------------------------------------
// DPP reduction: 4 butterfly stages -> row-uniform, 2 row_bcast adds -> total
// in lanes 48..63, readlane 63 -> wave-uniform scalar.
// ---------------------------------------------------------------------------
template <int CTRL, int RMASK, bool BC>
__device__ __forceinline__ float dpp_add(float v) {
  return v + __int_as_float(__builtin_amdgcn_update_dpp(
                 0, __float_as_int(v), CTRL, RMASK, 0xF, BC));
}
__device__ __forceinline__ float wave_red(float v) {
  v = dpp_add<0xB1, 0xF, true>(v);    // quad_perm xor 1
  v = dpp_add<0x4E, 0xF, true>(v);    // quad_perm xor 2
  v = dpp_add<0x141, 0xF, true>(v);   // row_half_mirror (xor 4)
  v = dpp_add<0x140, 0xF, true>(v);   // row_mirror (xor 8)
  v = dpp_add<0x142, 0xA, false>(v);  // row_bcast15 -> rows 1,3
  v = dpp_add<0x143, 0xC, false>(v);  // row_bcast31 -> rows 2,3
  return __int_as_float(__builtin_amdgcn_readlane(__float_as_int(v), 63));
}

// ---------------------------------------------------------------------------
// Kernel 1: proj[m, n] = dot(x[m, :], W[n, :])  (unchanged)
// ---------------------------------------------------------------------------
__global__ __launch_bounds__(256) void gemm_proj(const float* __restrict__ x,
                                                 const float* __restrict__ W,
                                                 float* __restrict__ proj) {
  __shared__ float xs[32][132];
  __shared__ float ws[32][132];
  const int tid = threadIdx.x;
  const int n0 = blockIdx.x * 128;
  const int m0 = blockIdx.y * 128;
  const int mi = tid >> 4;
  const int ni = tid & 15;

  float acc[8][8];
#pragma unroll
  for (int r = 0; r < 8; ++r)
#pragma unroll
    for (int c = 0; c < 8; ++c) acc[r][c] = 0.f;

  for (int k0 = 0; k0 < D_SZ; k0 += 32) {
#pragma unroll
    for (int rep = 0; rep < 4; ++rep) {
      const int f = tid + rep * 256;
      const int row = f >> 3;
      const int c4 = (f & 7) * 4;
      const float4 xv = *reinterpret_cast<const float4*>(
          &x[(size_t)(m0 + row) * D_SZ + k0 + c4]);
      xs[c4 + 0][row] = xv.x; xs[c4 + 1][row] = xv.y;
      xs[c4 + 2][row] = xv.z; xs[c4 + 3][row] = xv.w;
      const float4 wv = *reinterpret_cast<const float4*>(
          &W[(size_t)(n0 + row) * D_SZ + k0 + c4]);
      ws[c4 + 0][row] = wv.x; ws[c4 + 1][row] = wv.y;
      ws[c4 + 2][row] = wv.z; ws[c4 + 3][row] = wv.w;
    }
    __syncthreads();
#pragma unroll
    for (int k = 0; k < 32; ++k) {
      float av[8], bv[8];
      *reinterpret_cast<float4*>(&av[0]) =
          *reinterpret_cast<const float4*>(&xs[k][mi * 8]);
      *reinterpret_cast<float4*>(&av[4]) =
          *reinterpret_cast<const float4*>(&xs[k][mi * 8 + 4]);
      *reinterpret_cast<float4*>(&bv[0]) =
          *reinterpret_cast<const float4*>(&ws[k][ni * 8]);
      *reinterpret_cast<float4*>(&bv[4]) =
          *reinterpret_cast<const float4*>(&ws[k][ni * 8 + 4]);
#pragma unroll
      for (int r = 0; r < 8; ++r)
#pragma unroll
        for (int c = 0; c < 8; ++c)
          acc[r][c] = fmaf(av[r], bv[c], acc[r][c]);
    }
    __syncthreads();
  }

#pragma unroll
  for (int r = 0; r < 8; ++r) {
    const size_t row = (size_t)(m0 + mi * 8 + r);
    float4 o0, o1;
    o0.x = acc[r][0]; o0.y = acc[r][1]; o0.z = acc[r][2]; o0.w = acc[r][3];
    o1.x = acc[r][4]; o1.y = acc[r][5]; o1.z = acc[r][6]; o1.w = acc[r][7];
    *reinterpret_cast<float4*>(&proj[row * NOUT + n0 + ni * 8]) = o0;
    *reinterpret_cast<float4*>(&proj[row * NOUT + n0 + ni * 8 + 4]) = o1;
  }
}

// ---------------------------------------------------------------------------
// Kernel 2: per (t,b) row, in-place repack: [ (kn,q) x64 | (v,dec) x64 ]
// ---------------------------------------------------------------------------
__global__ __launch_bounds__(256) void norm_gate(float* __restrict__ proj,
                                                 const float* __restrict__ b_gate) {
  const int wid = threadIdx.x >> 6;
  const int lane = threadIdx.x & 63;
  const int m = blockIdx.x * 4 + wid;
  float* p = proj + (size_t)m * NOUT;
  const float kf = p[lane];
  const float vf = p[64 + lane];
  const float qf = p[128 + lane];
  const float gf = p[192 + lane];
  const float bg = b_gate[lane];
  const float ss = wave_red(kf * kf);
  const float kn = kf / (sqrtf(ss) + 1e-6f);
  const float dec = 1.f / (1.f + expf(-(gf + bg)));
  asm volatile("s_waitcnt vmcnt(0)" ::: "memory");
  float2* pp = reinterpret_cast<float2*>(p);
  float2 a; a.x = kn; a.y = qf;
  float2 c; c.x = vf; c.y = dec;
  pp[lane] = a;
  pp[64 + lane] = c;
}

// ---------------------------------------------------------------------------
// Kernel 3: Gram precompute (unchanged).
//   M[a][c] = kn_a . kn_c  (c > a) ; q_a . kn_c (c <= a, diag kn.q at [a][a])
// ---------------------------------------------------------------------------
__global__ __launch_bounds__(256) void gram_kernel(const float* __restrict__ proj,
                                                   float* __restrict__ gram) {
  const int wid = threadIdx.x >> 6;
  const int lane = threadIdx.x & 63;
  const int gw = blockIdx.x * 4 + wid;
  const int a = gw & 7;
  const int grp = gw >> 3;                  // b*NBLK + blk
  const int blk = grp & (NBLK - 1);
  const int b = grp >> 8;
  const int t0 = blk * U_BLK;
  const float2* base = reinterpret_cast<const float2*>(proj);

  float2 knq[8];
#pragma unroll
  for (int c = 0; c < 8; ++c)
    knq[c] = base[(size_t)((t0 + c) * B_SZ + b) * 128 + lane];
  const float2 mine = base[(size_t)((t0 + a) * B_SZ + b) * 128 + lane];

  float row[8];
#pragma unroll
  for (int c = 0; c < 8; ++c) {
    const float lhs = (c > a) ? mine.x : mine.y;
    row[c] = wave_red(lhs * knq[c].x);
  }
  if (lane == 0) {
    float* dst = gram + ((size_t)grp * 64 + a * 8);
    float4 r0, r1;
    r0.x = row[0]; r0.y = row[1]; r0.z = row[2]; r0.w = row[3];
    r1.x = row[4]; r1.y = row[5]; r1.z = row[6]; r1.w = row[7];
    *reinterpret_cast<float4*>(dst) = r0;
    *reinterpret_cast<float4*>(dst + 4) = r1;
  }
}

// ---------------------------------------------------------------------------
// Kernel 4: scan. 256 blocks x 4 waves.  XCD-friendly map: the 16 blocks
// sharing b have the same (bid % 8) -> same XCD L2 caches that b's proj rows.
// LDS double-buffered staging; factored UT-transform recurrence:
//   c(u) = prod_{t<u} dec_t ; d'_w = d_w / c(w+1)
//   d_u  = v_u - c(u)*(ra_u + sum_{w<u} d'_w G[w,u])
//   sq_u = c(u+1)*(rb_u + sum_{w<u} d'_w H[u,w]) + d_u*H[u,u]   (stored RAW)
//   S    = c(8) * (S + sum_w d'_w kn_w)
// Serial chain per step: fma -> mul -> fma (~15 cyc).
// ---------------------------------------------------------------------------
__global__ __launch_bounds__(256, 1) void scan_kernel(
    const float* __restrict__ proj, const float* __restrict__ gram,
    const float* __restrict__ S0, float* __restrict__ out,
    float* __restrict__ Sfin) {
  const int wid = threadIdx.x >> 6;     // 0..3
  const int lane = threadIdx.x & 63;
  const int bid = blockIdx.x;
  const int b = (bid & 7) | ((bid >> 7) << 3);     // same XCD for same b
  const int i = (((bid >> 3) & 15) << 2) | wid;

  __shared__ float lds[2][U_BLK * 256 + 64];   // 2 x 8448 B

  float S = S0[(size_t)b * 4096 + i * 64 + lane];

  const int r0 = wid * 2;           // this wave stages rows r0, r0+1
  float4 st0, st1;
  float stg = 0.f;

#define STAGE_LOAD(blkv)                                                      \
  {                                                                           \
    const size_t g0 = ((size_t)(((blkv) * U_BLK + r0) * B_SZ + b)) * NOUT;    \
    st0 = *reinterpret_cast<const float4*>(&proj[g0 + lane * 4]);             \
    st1 = *reinterpret_cast<const float4*>(&proj[g0 + (size_t)B_SZ * NOUT +   \
                                                 lane * 4]);                  \
    if (wid == 0) stg = gram[((size_t)b * NBLK + (blkv)) * 64 + lane];        \
  }

#define STAGE_WRITE(bufv)                                                     \
  {                                                                           \
    *reinterpret_cast<float4*>(&lds[bufv][r0 * 256 + lane * 4]) = st0;        \
    *reinterpret_cast<float4*>(&lds[bufv][(r0 + 1) * 256 + lane * 4]) = st1;  \
    if (wid == 0) lds[bufv][U_BLK * 256 + lane] = stg;                        \
  }

#define GM(idx) __int_as_float(                                               \
    __builtin_amdgcn_readlane(__float_as_int(gv), (idx)))

  STAGE_LOAD(0)
  STAGE_WRITE(0)
  __syncthreads();

  for (int blk = 0; blk < NBLK; ++blk) {
    const int buf = blk & 1;
    if (blk + 1 < NBLK) STAGE_LOAD(blk + 1)

    // ---- compute block blk from lds[buf] ----
    float2 knqv[8], vdv[8];
#pragma unroll
    for (int u = 0; u < 8; ++u) {
      knqv[u] = *reinterpret_cast<const float2*>(&lds[buf][u * 256 + lane * 2]);
      vdv[u] = *reinterpret_cast<const float2*>(&lds[buf][u * 256 + 128 + i * 2]);
    }
    const float gv = lds[buf][U_BLK * 256 + lane];

    // prefix products + reciprocals (overlaps the reductions below)
    float c[9], rc[8];
    c[0] = 1.f;
#pragma unroll
    for (int u = 0; u < 8; ++u) {
      c[u + 1] = c[u] * vdv[u].y;
      rc[u] = __builtin_amdgcn_rcpf(c[u + 1]);
    }

    float acc[8], sac[8];
#pragma unroll
    for (int u = 0; u < 8; ++u) acc[u] = wave_red(S * knqv[u].x);
#pragma unroll
    for (int u = 0; u < 8; ++u) sac[u] = wave_red(S * knqv[u].y);

    float dp[8], sqv[8];
#pragma unroll
    for (int w = 0; w < 8; ++w) {
      const float d = fmaf(-c[w], acc[w], vdv[w].x);
      dp[w] = d * rc[w];
      sqv[w] = fmaf(c[w + 1], sac[w], d * GM(w * 8 + w));
#pragma unroll
      for (int u = w + 1; u < 8; ++u) {
        acc[u] = fmaf(dp[w], GM(w * 8 + u), acc[u]);   // G[w][u]
        sac[u] = fmaf(dp[w], GM(u * 8 + w), sac[u]);   // H[u][w]
      }
    }
    float tacc = S;
#pragma unroll
    for (int w = 0; w < 8; ++w) tacc = fmaf(dp[w], knqv[w].x, tacc);
    S = c[8] * tacc;

    if (lane == 0) {
      const size_t ob = (size_t)blk * U_BLK * (B_SZ * N_SZ) + b * N_SZ + i;
#pragma unroll
      for (int u = 0; u < 8; ++u)
        out[ob + (size_t)u * (B_SZ * N_SZ)] = sqv[u];   // raw sq; silu later
    }
    // ---- end compute ----

    if (blk + 1 < NBLK) STAGE_WRITE((blk + 1) & 1)
    __syncthreads();
  }

  Sfin[(size_t)b * 4096 + i * 64 + lane] = S;
#undef STAGE_LOAD
#undef STAGE_WRITE
#undef GM
}

// ---------------------------------------------------------------------------
// Kernel 5: postprocess out <- sq * silu(sq) = sq^2 * sigmoid(sq).
// 2048 blocks x 256 threads x float4 == 2,097,152 elements exactly.
// ---------------------------------------------------------------------------
__global__ __launch_bounds__(256) void silu_pp(float* __restrict__ o) {
  const size_t idx = ((size_t)blockIdx.x * 256 + threadIdx.x) * 4;
  float4 v = *reinterpret_cast<float4*>(&o[idx]);
  v.x = v.x * v.x * __fdividef(1.f, 1.f + __expf(-v.x));
  v.y = v.y * v.y * __fdividef(1.f, 1.f + __expf(-v.y));
  v.z = v.z * v.z * __fdividef(1.f, 1.f + __expf(-v.z));
  v.w = v.w * v.w * __fdividef(1.f, 1.f + __expf(-v.w));
  *reinterpret_cast<float4*>(&o[idx]) = v;
}

// ---------------------------------------------------------------------------
extern "C" void kernel_launch(void* const* d_in, const int* in_sizes, int n_in,
                              void* d_out, int out_size, void* d_ws, size_t ws_size,
                              hipStream_t stream) {
  const float* x      = (const float*)d_in[0];
  const float* S0     = (const float*)d_in[1];
  const float* W      = (const float*)d_in[2];
  const float* b_gate = (const float*)d_in[3];
  float* out  = (float*)d_out;
  float* proj = (float*)d_ws;                       // 33.55 MB
  float* gram = (float*)((char*)d_ws + (size_t)M_ROWS * NOUT * 4);  // +1 MB

  hipLaunchKernelGGL(gemm_proj, dim3(2, M_ROWS / 128), dim3(256), 0, stream,
                     x, W, proj);
  hipLaunchKernelGGL(norm_gate, dim3(M_ROWS / 4), dim3(256), 0, stream,
                     proj, b_gate);
  hipLaunchKernelGGL(gram_kernel, dim3(32768 / 4), dim3(256), 0, stream,
                     proj, gram);
  hipLaunchKernelGGL(scan_kernel, dim3(256), dim3(256), 0, stream,
                     proj, gram, S0, out, out + (size_t)T_STEPS * B_SZ * N_SZ);
  hipLaunchKernelGGL(silu_pp, dim3(2048), dim3(256), 0, stream, out);
}

// Round 8
// 490.797 us; speedup vs baseline: 1.5831x; 1.2036x over previous
//
#include <hip/hip_runtime.h>
#include <math.h>

#define T_STEPS 2048
#define B_SZ 16
#define D_SZ 1024
#define N_SZ 64
#define M_ROWS (T_STEPS * B_SZ)   // 32768
#define NOUT (4 * N_SZ)           // 256
#define U_BLK 8
#define NBLK (T_STEPS / U_BLK)    // 256

typedef __attribute__((ext_vector_type(8))) short bf16x8;
typedef __attribute__((ext_vector_type(4))) float f32x4;

// ---------------------------------------------------------------------------
// DPP reduction (unchanged, verified R4-R6).
// ---------------------------------------------------------------------------
template <int CTRL, int RMASK, bool BC>
__device__ __forceinline__ float dpp_add(float v) {
  return v + __int_as_float(__builtin_amdgcn_update_dpp(
                 0, __float_as_int(v), CTRL, RMASK, 0xF, BC));
}
__device__ __forceinline__ float wave_red(float v) {
  v = dpp_add<0xB1, 0xF, true>(v);    // quad_perm xor 1
  v = dpp_add<0x4E, 0xF, true>(v);    // quad_perm xor 2
  v = dpp_add<0x141, 0xF, true>(v);   // row_half_mirror (xor 4)
  v = dpp_add<0x140, 0xF, true>(v);   // row_mirror (xor 8)
  v = dpp_add<0x142, 0xA, false>(v);  // row_bcast15 -> rows 1,3
  v = dpp_add<0x143, 0xC, false>(v);  // row_bcast31 -> rows 2,3
  return __int_as_float(__builtin_amdgcn_readlane(__float_as_int(v), 63));
}

__device__ __forceinline__ unsigned short f2bf(float f) {
  union { float f; unsigned u; } c; c.f = f;
  const unsigned r = c.u + 0x7FFFu + ((c.u >> 16) & 1u);   // RNE
  return (unsigned short)(r >> 16);
}

// ---------------------------------------------------------------------------
// Kernel 1: proj = x @ W^T via bf16 MFMA.  BM=64 (x read once), BN=256, BK=64.
// 256 threads = 4 waves; wave w owns n-cols [w*64, w*64+64), 4x4 16x16 tiles.
// LDS rows padded to 72 ushorts (144B): 16B aligned, capacity-only conflicts.
// Frag layouts (guide-verified): A/B lane holds 8 contiguous-k bf16 at
// row (lane&15), k-off (lane>>4)*8;  C/D col=lane&15, row=(lane>>4)*4+reg.
// ---------------------------------------------------------------------------
__global__ __launch_bounds__(256) void gemm_proj(const float* __restrict__ x,
                                                 const float* __restrict__ W,
                                                 float* __restrict__ proj) {
  __shared__ unsigned short Al[64][72];
  __shared__ unsigned short Bl[256][72];
  const int tid = threadIdx.x;
  const int lane = tid & 63;
  const int wv = tid >> 6;
  const int m0 = blockIdx.x * 64;
  const int nw0 = wv * 64;

  f32x4 acc[4][4];
#pragma unroll
  for (int m = 0; m < 4; ++m)
#pragma unroll
    for (int n = 0; n < 4; ++n) acc[m][n] = (f32x4){0.f, 0.f, 0.f, 0.f};

  const int arow = tid >> 2;          // 0..63
  const int akb = (tid & 3) * 16;     // 0,16,32,48

  for (int k0 = 0; k0 < D_SZ; k0 += 64) {
    // ---- stage A (64x64 fp32 -> bf16) ----
    {
      const float* src = &x[(size_t)(m0 + arow) * D_SZ + k0 + akb];
      unsigned short tmp[16];
#pragma unroll
      for (int c = 0; c < 4; ++c) {
        const float4 f = *reinterpret_cast<const float4*>(src + c * 4);
        tmp[c * 4 + 0] = f2bf(f.x); tmp[c * 4 + 1] = f2bf(f.y);
        tmp[c * 4 + 2] = f2bf(f.z); tmp[c * 4 + 3] = f2bf(f.w);
      }
      *reinterpret_cast<bf16x8*>(&Al[arow][akb]) =
          *reinterpret_cast<bf16x8*>(&tmp[0]);
      *reinterpret_cast<bf16x8*>(&Al[arow][akb + 8]) =
          *reinterpret_cast<bf16x8*>(&tmp[8]);
    }
    // ---- stage B (256x64): thread t -> W row t ----
    {
      const float* src = &W[(size_t)tid * D_SZ + k0];
#pragma unroll
      for (int h = 0; h < 4; ++h) {
        unsigned short tmp[16];
#pragma unroll
        for (int c = 0; c < 4; ++c) {
          const float4 f = *reinterpret_cast<const float4*>(src + h * 16 + c * 4);
          tmp[c * 4 + 0] = f2bf(f.x); tmp[c * 4 + 1] = f2bf(f.y);
          tmp[c * 4 + 2] = f2bf(f.z); tmp[c * 4 + 3] = f2bf(f.w);
        }
        *reinterpret_cast<bf16x8*>(&Bl[tid][h * 16]) =
            *reinterpret_cast<bf16x8*>(&tmp[0]);
        *reinterpret_cast<bf16x8*>(&Bl[tid][h * 16 + 8]) =
            *reinterpret_cast<bf16x8*>(&tmp[8]);
      }
    }
    __syncthreads();
    const int fr = lane & 15;
#pragma unroll
    for (int kk = 0; kk < 64; kk += 32) {
      const int kof = kk + (lane >> 4) * 8;
      bf16x8 af[4], bfr[4];
#pragma unroll
      for (int m = 0; m < 4; ++m)
        af[m] = *reinterpret_cast<const bf16x8*>(&Al[m * 16 + fr][kof]);
#pragma unroll
      for (int n = 0; n < 4; ++n)
        bfr[n] = *reinterpret_cast<const bf16x8*>(&Bl[nw0 + n * 16 + fr][kof]);
#pragma unroll
      for (int m = 0; m < 4; ++m)
#pragma unroll
        for (int n = 0; n < 4; ++n)
          acc[m][n] = __builtin_amdgcn_mfma_f32_16x16x32_bf16(
              af[m], bfr[n], acc[m][n], 0, 0, 0);
    }
    __syncthreads();
  }

  const int col = lane & 15;
  const int rb = (lane >> 4) * 4;
#pragma unroll
  for (int m = 0; m < 4; ++m)
#pragma unroll
    for (int n = 0; n < 4; ++n)
#pragma unroll
      for (int r = 0; r < 4; ++r)
        proj[(size_t)(m0 + m * 16 + rb + r) * NOUT + nw0 + n * 16 + col] =
            acc[m][n][r];
}

// ---------------------------------------------------------------------------
// Kernel 2: per (t,b) row, in-place repack: [ (kn,q) x64 | (v,dec) x64 ]
// ---------------------------------------------------------------------------
__global__ __launch_bounds__(256) void norm_gate(float* __restrict__ proj,
                                                 const float* __restrict__ b_gate) {
  const int wid = threadIdx.x >> 6;
  const int lane = threadIdx.x & 63;
  const int m = blockIdx.x * 4 + wid;
  float* p = proj + (size_t)m * NOUT;
  const float kf = p[lane];
  const float vf = p[64 + lane];
  const float qf = p[128 + lane];
  const float gf = p[192 + lane];
  const float bg = b_gate[lane];
  const float ss = wave_red(kf * kf);
  const float kn = kf / (sqrtf(ss) + 1e-6f);
  const float dec = 1.f / (1.f + expf(-(gf + bg)));
  asm volatile("s_waitcnt vmcnt(0)" ::: "memory");
  float2* pp = reinterpret_cast<float2*>(p);
  float2 a; a.x = kn; a.y = qf;
  float2 c; c.x = vf; c.y = dec;
  pp[lane] = a;
  pp[64 + lane] = c;
}

// ---------------------------------------------------------------------------
// Kernel 3: Gram precompute (unchanged).
// ---------------------------------------------------------------------------
__global__ __launch_bounds__(256) void gram_kernel(const float* __restrict__ proj,
                                                   float* __restrict__ gram) {
  const int wid = threadIdx.x >> 6;
  const int lane = threadIdx.x & 63;
  const int gw = blockIdx.x * 4 + wid;
  const int a = gw & 7;
  const int grp = gw >> 3;                  // b*NBLK + blk
  const int blk = grp & (NBLK - 1);
  const int b = grp >> 8;
  const int t0 = blk * U_BLK;
  const float2* base = reinterpret_cast<const float2*>(proj);

  float2 knq[8];
#pragma unroll
  for (int c = 0; c < 8; ++c)
    knq[c] = base[(size_t)((t0 + c) * B_SZ + b) * 128 + lane];
  const float2 mine = base[(size_t)((t0 + a) * B_SZ + b) * 128 + lane];

  float row[8];
#pragma unroll
  for (int c = 0; c < 8; ++c) {
    const float lhs = (c > a) ? mine.x : mine.y;
    row[c] = wave_red(lhs * knq[c].x);
  }
  if (lane == 0) {
    float* dst = gram + ((size_t)grp * 64 + a * 8);
    float4 r0, r1;
    r0.x = row[0]; r0.y = row[1]; r0.z = row[2]; r0.w = row[3];
    r1.x = row[4]; r1.y = row[5]; r1.z = row[6]; r1.w = row[7];
    *reinterpret_cast<float4*>(dst) = r0;
    *reinterpret_cast<float4*>(dst + 4) = r1;
  }
}

// ---------------------------------------------------------------------------
// Kernel 4: scan, 3-buffer pipeline.  Per iter:
//   LWRITE(blk+1) [regs loaded last iter] -> GLOAD(blk+2) -> barrier ->
//   RREAD(blk+1)->nxt regs (latency hides under compute) -> COMPUTE(blk).
// Compute math identical to R6 (factored UT-transform recurrence).
// ---------------------------------------------------------------------------
__global__ __launch_bounds__(256, 1) void scan_kernel(
    const float* __restrict__ proj, const float* __restrict__ gram,
    const float* __restrict__ S0, float* __restrict__ out,
    float* __restrict__ Sfin) {
  const int wid = threadIdx.x >> 6;     // 0..3
  const int lane = threadIdx.x & 63;
  const int bid = blockIdx.x;
  const int b = (bid & 7) | ((bid >> 7) << 3);     // same XCD for same b
  const int i = (((bid >> 3) & 15) << 2) | wid;

  __shared__ float lds[3][U_BLK * 256 + 64];   // 3 x 8448 floats = 99 KB

  float S = S0[(size_t)b * 4096 + i * 64 + lane];
  const int r0 = wid * 2;

  float4 sA0, sA1, sB0, sB1;
  float gA = 0.f, gB = 0.f;

#define GLOAD(s0, s1, sg, blkv)                                               \
  {                                                                           \
    const size_t g0 = ((size_t)(((blkv) * U_BLK + r0) * B_SZ + b)) * NOUT;    \
    s0 = *reinterpret_cast<const float4*>(&proj[g0 + lane * 4]);              \
    s1 = *reinterpret_cast<const float4*>(&proj[g0 + (size_t)B_SZ * NOUT +    \
                                                lane * 4]);                   \
    if (wid == 0) sg = gram[((size_t)b * NBLK + (blkv)) * 64 + lane];         \
  }

#define LWRITE(s0, s1, sg, bufv)                                              \
  {                                                                           \
    *reinterpret_cast<float4*>(&lds[bufv][r0 * 256 + lane * 4]) = s0;         \
    *reinterpret_cast<float4*>(&lds[bufv][(r0 + 1) * 256 + lane * 4]) = s1;   \
    if (wid == 0) lds[bufv][U_BLK * 256 + lane] = sg;                         \
  }

#define RREAD(bufv, knq, vd, gvv)                                             \
  {                                                                           \
    _Pragma("unroll")                                                         \
    for (int u = 0; u < 8; ++u) {                                             \
      knq[u] = *reinterpret_cast<const float2*>(                              \
          &lds[bufv][u * 256 + lane * 2]);                                    \
      vd[u] = *reinterpret_cast<const float2*>(                               \
          &lds[bufv][u * 256 + 128 + i * 2]);                                 \
    }                                                                         \
    gvv = lds[bufv][U_BLK * 256 + lane];                                      \
  }

#define GM(idx) __int_as_float(                                               \
    __builtin_amdgcn_readlane(__float_as_int(gv), (idx)))

  float2 knqC[8], vdC[8], knqN[8], vdN[8];
  float gvC = 0.f, gvN = 0.f;

  GLOAD(sA0, sA1, gA, 0)
  LWRITE(sA0, sA1, gA, 0)
  GLOAD(sB0, sB1, gB, 1)
  __syncthreads();
  RREAD(0, knqC, vdC, gvC)

  int wbuf = 1;
  for (int blk = 0; blk < NBLK; ++blk) {
    if (blk + 1 < NBLK) {
      if ((blk & 1) == 0) LWRITE(sB0, sB1, gB, wbuf)
      else                LWRITE(sA0, sA1, gA, wbuf)
    }
    if (blk + 2 < NBLK) {
      if ((blk & 1) == 0) GLOAD(sA0, sA1, gA, blk + 2)
      else                GLOAD(sB0, sB1, gB, blk + 2)
    }
    __syncthreads();
    if (blk + 1 < NBLK) RREAD(wbuf, knqN, vdN, gvN)

    // ---- compute block blk (identical math to R6) ----
    const float gv = gvC;
    float c[9], rc[8];
    c[0] = 1.f;
#pragma unroll
    for (int u = 0; u < 8; ++u) {
      c[u + 1] = c[u] * vdC[u].y;
      rc[u] = __builtin_amdgcn_rcpf(c[u + 1]);
    }

    float acc[8], sac[8];
#pragma unroll
    for (int u = 0; u < 8; ++u) acc[u] = wave_red(S * knqC[u].x);
#pragma unroll
    for (int u = 0; u < 8; ++u) sac[u] = wave_red(S * knqC[u].y);

    float dp[8], sqv[8];
#pragma unroll
    for (int w = 0; w < 8; ++w) {
      const float d = fmaf(-c[w], acc[w], vdC[w].x);
      dp[w] = d * rc[w];
      sqv[w] = fmaf(c[w + 1], sac[w], d * GM(w * 8 + w));
#pragma unroll
      for (int u = w + 1; u < 8; ++u) {
        acc[u] = fmaf(dp[w], GM(w * 8 + u), acc[u]);   // G[w][u]
        sac[u] = fmaf(dp[w], GM(u * 8 + w), sac[u]);   // H[u][w]
      }
    }
    float tacc = S;
#pragma unroll
    for (int w = 0; w < 8; ++w) tacc = fmaf(dp[w], knqC[w].x, tacc);
    S = c[8] * tacc;

    if (lane == 0) {
      const size_t ob = (size_t)blk * U_BLK * (B_SZ * N_SZ) + b * N_SZ + i;
#pragma unroll
      for (int u = 0; u < 8; ++u)
        out[ob + (size_t)u * (B_SZ * N_SZ)] = sqv[u];   // raw sq; silu later
    }
    // ---- end compute ----

    if (blk + 1 < NBLK) {
#pragma unroll
      for (int u = 0; u < 8; ++u) { knqC[u] = knqN[u]; vdC[u] = vdN[u]; }
      gvC = gvN;
      wbuf = (wbuf == 2) ? 0 : wbuf + 1;
    }
  }

  Sfin[(size_t)b * 4096 + i * 64 + lane] = S;
#undef GLOAD
#undef LWRITE
#undef RREAD
#undef GM
}

// ---------------------------------------------------------------------------
// Kernel 5: out <- sq^2 * sigmoid(sq).  2048*256*4 = 2,097,152 elems exactly.
// ---------------------------------------------------------------------------
__global__ __launch_bounds__(256) void silu_pp(float* __restrict__ o) {
  const size_t idx = ((size_t)blockIdx.x * 256 + threadIdx.x) * 4;
  float4 v = *reinterpret_cast<float4*>(&o[idx]);
  v.x = v.x * v.x * __fdividef(1.f, 1.f + __expf(-v.x));
  v.y = v.y * v.y * __fdividef(1.f, 1.f + __expf(-v.y));
  v.z = v.z * v.z * __fdividef(1.f, 1.f + __expf(-v.z));
  v.w = v.w * v.w * __fdividef(1.f, 1.f + __expf(-v.w));
  *reinterpret_cast<float4*>(&o[idx]) = v;
}

// ---------------------------------------------------------------------------
extern "C" void kernel_launch(void* const* d_in, const int* in_sizes, int n_in,
                              void* d_out, int out_size, void* d_ws, size_t ws_size,
                              hipStream_t stream) {
  const float* x      = (const float*)d_in[0];
  const float* S0     = (const float*)d_in[1];
  const float* W      = (const float*)d_in[2];
  const float* b_gate = (const float*)d_in[3];
  float* out  = (float*)d_out;
  float* proj = (float*)d_ws;                       // 33.55 MB
  float* gram = (float*)((char*)d_ws + (size_t)M_ROWS * NOUT * 4);  // +1 MB

  hipLaunchKernelGGL(gemm_proj, dim3(M_ROWS / 64), dim3(256), 0, stream,
                     x, W, proj);
  hipLaunchKernelGGL(norm_gate, dim3(M_ROWS / 4), dim3(256), 0, stream,
                     proj, b_gate);
  hipLaunchKernelGGL(gram_kernel, dim3(32768 / 4), dim3(256), 0, stream,
                     proj, gram);
  hipLaunchKernelGGL(scan_kernel, dim3(256), dim3(256), 0, stream,
                     proj, gram, S0, out, out + (size_t)T_STEPS * B_SZ * N_SZ);
  hipLaunchKernelGGL(silu_pp, dim3(2048), dim3(256), 0, stream, out);
}